// Round 18
// baseline (185.483 us; speedup 1.0000x reference)
//
#include <hip/hip_runtime.h>
#include <cstdint>

#define NEG (-1e12f)
constexpr int Bn = 32, Ln = 256, Tn = 2048;
constexpr int TB = Tn / 64;                 // 32 uint64 words of t-bits per text row

// d_ws layout (bytes):
//   bits    @ 0       : 32*256*32*8 = 2,097,152
//   partial @ 2097152 : 1024 floats (4 KB)

// lane i <- lane (i-1)&63  (wave_ror:1) : torch-wrap neighbor for the bit compare
__device__ inline float dpp_ror1(float x) {
    int xi = __float_as_int(x);
    return __int_as_float(__builtin_amdgcn_update_dpp(xi, xi, 0x13C, 0xF, 0xF, false));
}

__device__ inline uint32_t lds_off(const void* p) {
    return (uint32_t)(uintptr_t)(__attribute__((address_space(3))) const void*)p;
}

// raw barrier: NO implicit counter drain (producers' global loads stay in flight)
#define BARRIER() { asm volatile("" ::: "memory"); \
                    __builtin_amdgcn_s_barrier(); \
                    asm volatile("" ::: "memory"); }

// swizzled ds_read_b128: element (t,l) at col l ^ (16*bit2(t));
// lane block byte = (16*lane) ^ (64*bit2(row)).  ROW, BUF compile-time.
#define DSRX(DST, ROW, BUF) \
    asm volatile("ds_read_b128 %0, %1 offset:%c2" \
        : "=&v"(DST) \
        : "v"((((ROW) >> 2) & 1) ? vxb : vxa), \
          "i"((BUF) * 16384 + ((ROW) & 15) * 1024));

// coarse consume gate: once per 4 steps (r13-proven)
#define W4 { asm volatile("s_waitcnt lgkmcnt(4)"); __builtin_amdgcn_sched_barrier(0); }

// shift-accumulate one comparison bit: ACC = (ACC<<1) | (X > Y).  (r14-proven;
// vcc chain fully pipelined — beats the 3-op path, r15.) Bits land MSB-first;
// the walk bit-reverses each word on load.
#define ABIT(ACC, X, Y) \
    asm("v_cmp_gt_f32 vcc, %1, %2\n\tv_addc_co_u32 %0, vcc, %0, %0, vcc" \
        : "+v"(ACC) : "v"(X), "v"(Y) : "vcc");

// r14-proven partial-deferral step with addc bit packing. S = t-64m (1..64).
#define STEPS(S, Q) { \
    if ((((S) - 1) & 32) == 0) { ABIT(a0hi, svp, pv0) } else { ABIT(a0lo, svp, pv0) } \
    float c3 = fmaxf(pv3, pv2) + (Q).w; \
    float sv = dpp_ror1(c3); \
    float c2 = fmaxf(pv2, pv1) + (Q).z; \
    float c1 = fmaxf(pv1, pv0) + (Q).y; \
    float lf = isl0 ? negc : svp; \
    float c0 = fmaxf(pv0, lf) + (Q).x; \
    if (((S) & 32) == 0) { \
        ABIT(a1hi, c0, c1) ABIT(a2hi, c1, c2) ABIT(a3hi, c2, c3) \
    } else { \
        ABIT(a1lo, c0, c1) ABIT(a2lo, c1, c2) ABIT(a3lo, c2, c3) \
    } \
    if ((S) == 63) { \
        bb[(size_t)(4 * lane + 1) * TB + m] = ((uint64_t)a1hi << 32) | a1lo; \
        bb[(size_t)(4 * lane + 2) * TB + m] = ((uint64_t)a2hi << 32) | a2lo; \
        bb[(size_t)(4 * lane + 3) * TB + m] = ((uint64_t)a3hi << 32) | a3lo; \
        a1lo = a1hi = a2lo = a2hi = a3lo = a3hi = 0; \
    } \
    if ((S) == 64) { \
        bb[(size_t)(4 * lane + 0) * TB + m] = ((uint64_t)a0hi << 32) | a0lo; \
        a0lo = a0hi = 0; \
    } \
    pv0 = c0; pv1 = c1; pv2 = c2; pv3 = c3; svp = sv; }

// 16 DP steps of chunk c = 4m+I (buffer I); 8 slots, 4-step groups (r13 schedule)
#define COMP16X(I) { \
    W4 \
    STEPS(16*(I)+ 1, qq0) STEPS(16*(I)+ 2, qq1) STEPS(16*(I)+ 3, qq2) STEPS(16*(I)+ 4, qq3) \
    DSRX(qq0,  9, (I)) DSRX(qq1, 10, (I)) DSRX(qq2, 11, (I)) DSRX(qq3, 12, (I)) \
    W4 \
    STEPS(16*(I)+ 5, qq4) STEPS(16*(I)+ 6, qq5) STEPS(16*(I)+ 7, qq6) STEPS(16*(I)+ 8, qq7) \
    DSRX(qq4, 13, (I)) DSRX(qq5, 14, (I)) DSRX(qq6, 15, (I)) DSRX(qq7,  0, ((I)+1)&3) \
    W4 \
    STEPS(16*(I)+ 9, qq0) STEPS(16*(I)+10, qq1) STEPS(16*(I)+11, qq2) STEPS(16*(I)+12, qq3) \
    DSRX(qq0,  1, ((I)+1)&3) DSRX(qq1,  2, ((I)+1)&3) DSRX(qq2,  3, ((I)+1)&3) DSRX(qq3,  4, ((I)+1)&3) \
    W4 \
    STEPS(16*(I)+13, qq4) STEPS(16*(I)+14, qq5) STEPS(16*(I)+15, qq6) STEPS(16*(I)+16, qq7) \
    DSRX(qq4,  5, ((I)+1)&3) DSRX(qq5,  6, ((I)+1)&3) DSRX(qq6,  7, ((I)+1)&3) DSRX(qq7,  8, ((I)+1)&3) \
    BARRIER() }

// producer reg-staged load of chunk P (t = 16P..16P+15), 6 float4 per thread
#define PLOAD(P) { \
    xh0 = *(const float4*)(pr0 + 16 * (P)); \
    xh1 = *(const float4*)(pr1 + 16 * (P)); \
    xh2 = *(const float4*)(pr2 + 16 * (P)); \
    xh3 = *(const float4*)(pr3 + 16 * (P)); \
    xh4 = *(const float4*)(pr4 + 16 * (P)); \
    if (six) xh5 = *(const float4*)(pr5 + 16 * (P)); }

#define PW1(XH, CC) { float* rq = rr + (CC); \
    rq[0] = (XH).x; rq[256] = (XH).y; rq[512] = (XH).z; rq[768] = (XH).w; }

#define PWRITE(P) { \
    float* rr = smem + ((P) & 3) * 4096; \
    PW1(xh0, c0) PW1(xh1, c1) PW1(xh2, c2) PW1(xh3, c3) PW1(xh4, c4) \
    if (six) PW1(xh5, c5) }

// ===== mega: 0..31 forward+staging | 32..1055 loss | 1056..1279 paced zero-fill =====
// smem = 96 KB: 1 block/CU (r14-proven). Forward/producer/loss branches are
// byte-identical to r14/r17. Zero riders (224 blocks, ~1 per free CU, dispatched
// after the loss burst) are PACED with s_sleep so the 64 MB write spreads over
// ~50 us (~1.3 TB/s) instead of a ~6 TB/s burst that starves the forward.
__global__ void __launch_bounds__(256, 1) k_mega(
        const float* __restrict__ logp, const float* __restrict__ att,
        const int* __restrict__ ilen, const int* __restrict__ olen,
        uint64_t* __restrict__ bits, float* __restrict__ partial,
        float* __restrict__ out) {
    __shared__ __align__(16) float smem[24576];   // 96 KB (ring = first 64 KB)
    int bid = blockIdx.x, tid = threadIdx.x;

    if (bid < 32) {
        int b = bid;
        if (tid < 64) {
            // ---------------- DP consumer wave ----------------
            __builtin_amdgcn_s_setprio(1);
            int lane = tid;
            bool isl0 = (lane == 0);
            uint64_t* bb = bits + (size_t)b * (Ln * TB);
            const float negc = NEG;
            uint32_t lb = lds_off(smem) + (uint32_t)(lane * 16);
            uint32_t vxa = lb, vxb = lb ^ 64;     // swizzle base pair

            float pv0, pv1, pv2, pv3, svp;
            uint32_t a0lo = 0, a0hi = 0, a1lo = 0, a1hi = 0;
            uint32_t a2lo = 0, a2hi = 0, a3lo = 0, a3hi = 0;

            // peeled t = 0: row0 = logp[b,0,0], others NEG.
            {
                float lp00 = logp[(size_t)b * (Ln * Tn)];
                pv0 = isl0 ? lp00 : NEG;
                pv1 = NEG; pv2 = NEG; pv3 = NEG;
                svp = dpp_ror1(pv3);               // all NEG
                a1hi = (pv0 > pv1) ? 1u : 0u;      // bit(0, 4*lane+1)
                a2hi = (pv1 > pv2) ? 1u : 0u;      // 0
                a3hi = (pv2 > pv3) ? 1u : 0u;      // 0
            }

            BARRIER();                             // chunks 0,1 in LDS; chunk 2 staged in regs
            float4 qq0, qq1, qq2, qq3, qq4, qq5, qq6, qq7;
            DSRX(qq0, 1, 0) DSRX(qq1, 2, 0) DSRX(qq2, 3, 0) DSRX(qq3, 4, 0)
            DSRX(qq4, 5, 0) DSRX(qq5, 6, 0) DSRX(qq6, 7, 0) DSRX(qq7, 8, 0)

            for (int m = 0; m < 32; ++m) {
                COMP16X(0) COMP16X(1) COMP16X(2) COMP16X(3)
            }
            asm volatile("s_waitcnt vmcnt(0)" ::: "memory");  // bit flushes visible
        } else {
            // -------- producer waves: stage logp -> LDS ring, transposed + swizzled --------
            int tid2 = tid - 64;                         // 0..191
            bool six = (tid2 < 64);                      // wave-uniform extra element
            const float* lpb = logp + (size_t)b * (Ln * Tn);
            int v0 = tid2, v1 = tid2 + 192, v2 = tid2 + 384,
                v3 = tid2 + 576, v4 = tid2 + 768, v5 = tid2 + 960;
            const float* pr0 = lpb + (size_t)(v0 >> 2) * Tn + 4 * (v0 & 3);
            const float* pr1 = lpb + (size_t)(v1 >> 2) * Tn + 4 * (v1 & 3);
            const float* pr2 = lpb + (size_t)(v2 >> 2) * Tn + 4 * (v2 & 3);
            const float* pr3 = lpb + (size_t)(v3 >> 2) * Tn + 4 * (v3 & 3);
            const float* pr4 = lpb + (size_t)(v4 >> 2) * Tn + 4 * (v4 & 3);
            const float* pr5 = lpb + (size_t)(v5 >> 2) * Tn + 4 * (v5 & 3);
            // col = l ^ (16*bit2(t)); bit2(t) = v&1 for this slot mapping
            int c0 = (4 * (v0 & 3)) * 256 + ((v0 >> 2) ^ ((v0 & 1) << 4));
            int c1 = (4 * (v1 & 3)) * 256 + ((v1 >> 2) ^ ((v1 & 1) << 4));
            int c2 = (4 * (v2 & 3)) * 256 + ((v2 >> 2) ^ ((v2 & 1) << 4));
            int c3 = (4 * (v3 & 3)) * 256 + ((v3 >> 2) ^ ((v3 & 1) << 4));
            int c4 = (4 * (v4 & 3)) * 256 + ((v4 >> 2) ^ ((v4 & 1) << 4));
            int c5 = (4 * (v5 & 3)) * 256 + ((v5 >> 2) ^ ((v5 & 1) << 4));
            float4 xh0, xh1, xh2, xh3, xh4, xh5;

            PLOAD(0) PWRITE(0)                 // prologue: chunks 0,1 in LDS; chunk 2 in regs
            PLOAD(1) PWRITE(1)
            PLOAD(2)
            asm volatile("s_waitcnt lgkmcnt(0)" ::: "memory");
            BARRIER();

            for (int k = 0; k < 128; ++k) {
                if (k <= 125) PWRITE(k + 2)    // write chunk staged last iteration
                if (k <= 124) PLOAD(k + 3)     // loads span the barrier (raw s_barrier)
                asm volatile("s_waitcnt lgkmcnt(0)" ::: "memory");
                BARRIER();
            }
        }
    } else if (bid < 32 + 1024) {
        // ---------------- guided-attention loss partials (independent blocks) ----------------
        const int N4 = Bn * Tn * Ln / 4;
        int j = bid - 32;
        int idx = j * 256 + tid;
        int stride = 1024 * 256;
        float acc = 0.f;
        for (int v = idx; v < N4; v += stride) {
            int flat = v << 2;                   // att is (B, T, L)
            int b  = flat >> 19;
            int t  = (flat >> 8) & (Tn - 1);
            int l0 = flat & (Ln - 1);
            int ili = ilen[b];
            int oli = olen[b];
            if (t >= oli) continue;
            float il = (float)ili, ol = (float)oli;
            float tf = (float)t / ol;
            float4 a = reinterpret_cast<const float4*>(att)[v];
            #pragma unroll
            for (int c = 0; c < 4; ++c) {
                int l = l0 + c;
                float av = (c == 0) ? a.x : (c == 1) ? a.y : (c == 2) ? a.z : a.w;
                if (l < ili) {
                    float d = (float)l / il - tf;
                    acc += (1.f - __expf(-d * d * 3.125f)) * av;
                }
            }
        }
        for (int off = 32; off > 0; off >>= 1) acc += __shfl_down(acc, off, 64);
        float* sw = smem;
        if ((tid & 63) == 0) sw[tid >> 6] = acc;
        __syncthreads();
        if (tid == 0) partial[j] = (sw[0] + sw[1]) + (sw[2] + sw[3]);
    } else {
        // -------- paced zero-fill riders: 64 MB spread over ~50 us (~1.3 TB/s) --------
        const int NZ = (Bn * Ln * Tn) / 4;       // 2,097,152 float4 groups
        int j = bid - 1056;                       // 0..223
        float4 z = make_float4(0.f, 0.f, 0.f, 0.f);
        for (int i = j * 256 + tid; i < NZ; i += 224 * 256) {
            reinterpret_cast<float4*>(out)[i] = z;
            asm volatile("s_sleep 48");          // ~3072 cy ~= 1.3 us between sweeps
        }
        if (j == 0 && tid == 0) out[(size_t)Bn * Ln * Tn] = 0.f;  // last element
    }
}

// ===== tail: per-batch backtrack (LDS bits, lane-0 walk, 8-deep window)
//       + sparse ones-scatter + (block 0) final loss reduce. =====
__global__ void __launch_bounds__(256) k_tail(const uint64_t* __restrict__ bits,
                                              const int* __restrict__ ilen,
                                              const int* __restrict__ olen,
                                              const float* __restrict__ partial,
                                              float* __restrict__ out) {
    __shared__ uint64_t sb[Ln * TB];   // 64 KB bit store
    __shared__ int2 eb[Ln];            // per-row extents
    __shared__ float sw[4];
    int b = blockIdx.x, tid = threadIdx.x;
    eb[tid] = make_int2(1, 0);         // empty
    const ulonglong2* g = (const ulonglong2*)(bits + (size_t)b * (Ln * TB));
    ulonglong2* s2 = (ulonglong2*)sb;
    #pragma unroll
    for (int i = 0; i < 16; ++i) s2[i * 256 + tid] = g[i * 256 + tid];
    __syncthreads();

    if (tid == 0) {
        int tl = ilen[b], ml = olen[b];
        int r = tl - 1, hi = ml - 1, p = ml - 2;
        if (p < 0) { eb[r] = make_int2(0, hi); }
        else {
            int c = p >> 6, vd;
            uint64_t w0, w1, w2, w3, w4, w5, w6, w7;
            #define LDW(RR) __builtin_bitreverse64(sb[(RR) * TB + c])
            #define RELOAD() { \
                w0 = LDW(r); \
                w1 = LDW(r > 0 ? r - 1 : 0); \
                w2 = LDW(r > 1 ? r - 2 : 0); \
                w3 = LDW(r > 2 ? r - 3 : 0); \
                w4 = LDW(r > 3 ? r - 4 : 0); \
                w5 = LDW(r > 4 ? r - 5 : 0); \
                w6 = LDW(r > 5 ? r - 6 : 0); \
                w7 = LDW(r > 6 ? r - 7 : 0); \
                vd = 7; }
            RELOAD();
            while (true) {
                int pb = p & 63;
                uint64_t mask = (pb == 63) ? ~0ull : ((1ull << (pb + 1)) - 1ull);
                uint64_t mm = w0 & mask;
                if (mm == 0) {
                    p = (p & ~63) - 1;
                    if (p < 0) { eb[r] = make_int2(0, hi); break; }
                    c = p >> 6;
                    RELOAD();
                } else {
                    int q = 63 - __builtin_clzll(mm);
                    int tq = (p & ~63) + q;
                    eb[r] = make_int2(tq + 1, hi);
                    r -= 1;
                    if (r < 0) break;           // saturation: remaining rows stay empty
                    hi = tq;
                    p = tq - 1;
                    if (p < 0) { eb[r] = make_int2(0, hi); break; }
                    w0 = w1; w1 = w2; w2 = w3; w3 = w4; w4 = w5; w5 = w6; w6 = w7;
                    vd -= 1;
                    int nc = p >> 6;
                    if (nc != c || vd == 0) { c = nc; RELOAD(); }
                }
            }
            #undef RELOAD
            #undef LDW
        }
    }
    __syncthreads();

    // sparse scatter: thread tid owns text row tid; write its run of ones
    {
        int2 e = eb[tid];
        float* orow = out + 1 + (((size_t)b * Ln + tid) << 11);
        for (int t = e.x; t <= e.y; ++t) orow[t] = 1.f;
    }

    // final deterministic loss reduce (block 0; zero-fill already wrote out[0]=0)
    if (b == 0) {
        float acc = 0.f;
        for (int i = tid; i < 1024; i += 256) acc += partial[i];
        for (int off = 32; off > 0; off >>= 1) acc += __shfl_down(acc, off, 64);
        if ((tid & 63) == 0) sw[tid >> 6] = acc;
        __syncthreads();
        if (tid == 0) {
            float tot = (sw[0] + sw[1]) + (sw[2] + sw[3]);
            int so = 0;
            for (int i = 0; i < Bn; ++i) so += olen[i];
            out[0] = tot / (float)so;
        }
    }
}

extern "C" void kernel_launch(void* const* d_in, const int* in_sizes, int n_in,
                              void* d_out, int out_size, void* d_ws, size_t ws_size,
                              hipStream_t stream) {
    const float* logp = (const float*)d_in[0];
    const float* att  = (const float*)d_in[1];
    const int* tlen   = (const int*)d_in[2];
    const int* mlen   = (const int*)d_in[3];
    float* out = (float*)d_out;
    uint64_t* bits = (uint64_t*)d_ws;                            // 2 MB
    float* partial = (float*)((char*)d_ws + 2097152);            // 4 KB

    // 1) mega: forward DP (r14 exact) + loss partials + PACED zero-fill riders
    k_mega<<<32 + 1024 + 224, 256, 0, stream>>>(logp, att, tlen, mlen,
                                                bits, partial, out);
    // 2) tail: backtrack (8-deep window) + sparse ones-scatter + final loss reduce
    k_tail<<<Bn, 256, 0, stream>>>(bits, tlen, mlen, partial, out);
}

// Round 19
// 130.326 us; speedup vs baseline: 1.4232x; 1.4232x over previous
//
#include <hip/hip_runtime.h>
#include <cstdint>

#define NEG (-1e12f)
constexpr int Bn = 32, Ln = 256, Tn = 2048;
constexpr int TB = Tn / 64;                 // 32 uint64 words of t-bits per text row

// d_ws layout (bytes):
//   bits    @ 0       : 32*256*32*8 = 2,097,152
//   partial @ 2097152 : 1024 floats (4 KB)

// lane i <- lane (i-1)&63  (wave_ror:1) : torch-wrap neighbor for the bit compare
__device__ inline float dpp_ror1(float x) {
    int xi = __float_as_int(x);
    return __int_as_float(__builtin_amdgcn_update_dpp(xi, xi, 0x13C, 0xF, 0xF, false));
}

__device__ inline uint32_t lds_off(const void* p) {
    return (uint32_t)(uintptr_t)(__attribute__((address_space(3))) const void*)p;
}

// raw barrier: NO implicit counter drain (producers' global loads stay in flight)
#define BARRIER() { asm volatile("" ::: "memory"); \
                    __builtin_amdgcn_s_barrier(); \
                    asm volatile("" ::: "memory"); }

// swizzled ds_read_b128: element (t,l) at col l ^ (16*bit2(t));
// lane block byte = (16*lane) ^ (64*bit2(row)).  ROW, BUF compile-time.
#define DSRX(DST, ROW, BUF) \
    asm volatile("ds_read_b128 %0, %1 offset:%c2" \
        : "=&v"(DST) \
        : "v"((((ROW) >> 2) & 1) ? vxb : vxa), \
          "i"((BUF) * 16384 + ((ROW) & 15) * 1024));

// coarse consume gate: once per 4 steps (r13-proven)
#define W4 { asm volatile("s_waitcnt lgkmcnt(4)"); __builtin_amdgcn_sched_barrier(0); }

// shift-accumulate one comparison bit: ACC = (ACC<<1) | (X > Y).  (r14-proven;
// vcc chain fully pipelined — beats the 3-op path, r15.) Bits land MSB-first;
// the walk bit-reverses each word on load.
#define ABIT(ACC, X, Y) \
    asm("v_cmp_gt_f32 vcc, %1, %2\n\tv_addc_co_u32 %0, vcc, %0, %0, vcc" \
        : "+v"(ACC) : "v"(X), "v"(Y) : "vcc");

// r14-proven partial-deferral step with addc bit packing. S = t-64m (1..64).
#define STEPS(S, Q) { \
    if ((((S) - 1) & 32) == 0) { ABIT(a0hi, svp, pv0) } else { ABIT(a0lo, svp, pv0) } \
    float c3 = fmaxf(pv3, pv2) + (Q).w; \
    float sv = dpp_ror1(c3); \
    float c2 = fmaxf(pv2, pv1) + (Q).z; \
    float c1 = fmaxf(pv1, pv0) + (Q).y; \
    float lf = isl0 ? negc : svp; \
    float c0 = fmaxf(pv0, lf) + (Q).x; \
    if (((S) & 32) == 0) { \
        ABIT(a1hi, c0, c1) ABIT(a2hi, c1, c2) ABIT(a3hi, c2, c3) \
    } else { \
        ABIT(a1lo, c0, c1) ABIT(a2lo, c1, c2) ABIT(a3lo, c2, c3) \
    } \
    if ((S) == 63) { \
        bb[(size_t)(4 * lane + 1) * TB + m] = ((uint64_t)a1hi << 32) | a1lo; \
        bb[(size_t)(4 * lane + 2) * TB + m] = ((uint64_t)a2hi << 32) | a2lo; \
        bb[(size_t)(4 * lane + 3) * TB + m] = ((uint64_t)a3hi << 32) | a3lo; \
        a1lo = a1hi = a2lo = a2hi = a3lo = a3hi = 0; \
    } \
    if ((S) == 64) { \
        bb[(size_t)(4 * lane + 0) * TB + m] = ((uint64_t)a0hi << 32) | a0lo; \
        a0lo = a0hi = 0; \
    } \
    pv0 = c0; pv1 = c1; pv2 = c2; pv3 = c3; svp = sv; }

// 16 DP steps of chunk c = 4m+I (buffer I); 8 slots, 4-step groups (r13 schedule)
#define COMP16X(I) { \
    W4 \
    STEPS(16*(I)+ 1, qq0) STEPS(16*(I)+ 2, qq1) STEPS(16*(I)+ 3, qq2) STEPS(16*(I)+ 4, qq3) \
    DSRX(qq0,  9, (I)) DSRX(qq1, 10, (I)) DSRX(qq2, 11, (I)) DSRX(qq3, 12, (I)) \
    W4 \
    STEPS(16*(I)+ 5, qq4) STEPS(16*(I)+ 6, qq5) STEPS(16*(I)+ 7, qq6) STEPS(16*(I)+ 8, qq7) \
    DSRX(qq4, 13, (I)) DSRX(qq5, 14, (I)) DSRX(qq6, 15, (I)) DSRX(qq7,  0, ((I)+1)&3) \
    W4 \
    STEPS(16*(I)+ 9, qq0) STEPS(16*(I)+10, qq1) STEPS(16*(I)+11, qq2) STEPS(16*(I)+12, qq3) \
    DSRX(qq0,  1, ((I)+1)&3) DSRX(qq1,  2, ((I)+1)&3) DSRX(qq2,  3, ((I)+1)&3) DSRX(qq3,  4, ((I)+1)&3) \
    W4 \
    STEPS(16*(I)+13, qq4) STEPS(16*(I)+14, qq5) STEPS(16*(I)+15, qq6) STEPS(16*(I)+16, qq7) \
    DSRX(qq4,  5, ((I)+1)&3) DSRX(qq5,  6, ((I)+1)&3) DSRX(qq6,  7, ((I)+1)&3) DSRX(qq7,  8, ((I)+1)&3) \
    BARRIER() }

// producer reg-staged load of chunk P (t = 16P..16P+15), 6 float4 per thread
#define PLOAD(P) { \
    xh0 = *(const float4*)(pr0 + 16 * (P)); \
    xh1 = *(const float4*)(pr1 + 16 * (P)); \
    xh2 = *(const float4*)(pr2 + 16 * (P)); \
    xh3 = *(const float4*)(pr3 + 16 * (P)); \
    xh4 = *(const float4*)(pr4 + 16 * (P)); \
    if (six) xh5 = *(const float4*)(pr5 + 16 * (P)); }

#define PW1(XH, CC) { float* rq = rr + (CC); \
    rq[0] = (XH).x; rq[256] = (XH).y; rq[512] = (XH).z; rq[768] = (XH).w; }

#define PWRITE(P) { \
    float* rr = smem + ((P) & 3) * 4096; \
    PW1(xh0, c0) PW1(xh1, c1) PW1(xh2, c2) PW1(xh3, c3) PW1(xh4, c4) \
    if (six) PW1(xh5, c5) }

// ===== mega: 0..31 forward+staging | 32..1055 loss | 1056..1071 zero-fill =====
// smem = 96 KB: 1 block/CU (r14-proven). Forward/producer/loss branches are
// byte-identical to r14/r17. Zero riders: 16 blocks, UNPACED — issue-rate
// throttled (~1.2 TB/s aggregate: per-CU store stream cap), no s_sleep (r18's
// DVFS trap). 64 MB / 1.2 TB/s ~= 53 us, finishing inside forward's 92 us.
__global__ void __launch_bounds__(256, 1) k_mega(
        const float* __restrict__ logp, const float* __restrict__ att,
        const int* __restrict__ ilen, const int* __restrict__ olen,
        uint64_t* __restrict__ bits, float* __restrict__ partial,
        float* __restrict__ out) {
    __shared__ __align__(16) float smem[24576];   // 96 KB (ring = first 64 KB)
    int bid = blockIdx.x, tid = threadIdx.x;

    if (bid < 32) {
        int b = bid;
        if (tid < 64) {
            // ---------------- DP consumer wave ----------------
            __builtin_amdgcn_s_setprio(1);
            int lane = tid;
            bool isl0 = (lane == 0);
            uint64_t* bb = bits + (size_t)b * (Ln * TB);
            const float negc = NEG;
            uint32_t lb = lds_off(smem) + (uint32_t)(lane * 16);
            uint32_t vxa = lb, vxb = lb ^ 64;     // swizzle base pair

            float pv0, pv1, pv2, pv3, svp;
            uint32_t a0lo = 0, a0hi = 0, a1lo = 0, a1hi = 0;
            uint32_t a2lo = 0, a2hi = 0, a3lo = 0, a3hi = 0;

            // peeled t = 0: row0 = logp[b,0,0], others NEG.
            {
                float lp00 = logp[(size_t)b * (Ln * Tn)];
                pv0 = isl0 ? lp00 : NEG;
                pv1 = NEG; pv2 = NEG; pv3 = NEG;
                svp = dpp_ror1(pv3);               // all NEG
                a1hi = (pv0 > pv1) ? 1u : 0u;      // bit(0, 4*lane+1)
                a2hi = (pv1 > pv2) ? 1u : 0u;      // 0
                a3hi = (pv2 > pv3) ? 1u : 0u;      // 0
            }

            BARRIER();                             // chunks 0,1 in LDS; chunk 2 staged in regs
            float4 qq0, qq1, qq2, qq3, qq4, qq5, qq6, qq7;
            DSRX(qq0, 1, 0) DSRX(qq1, 2, 0) DSRX(qq2, 3, 0) DSRX(qq3, 4, 0)
            DSRX(qq4, 5, 0) DSRX(qq5, 6, 0) DSRX(qq6, 7, 0) DSRX(qq7, 8, 0)

            for (int m = 0; m < 32; ++m) {
                COMP16X(0) COMP16X(1) COMP16X(2) COMP16X(3)
            }
            asm volatile("s_waitcnt vmcnt(0)" ::: "memory");  // bit flushes visible
        } else {
            // -------- producer waves: stage logp -> LDS ring, transposed + swizzled --------
            int tid2 = tid - 64;                         // 0..191
            bool six = (tid2 < 64);                      // wave-uniform extra element
            const float* lpb = logp + (size_t)b * (Ln * Tn);
            int v0 = tid2, v1 = tid2 + 192, v2 = tid2 + 384,
                v3 = tid2 + 576, v4 = tid2 + 768, v5 = tid2 + 960;
            const float* pr0 = lpb + (size_t)(v0 >> 2) * Tn + 4 * (v0 & 3);
            const float* pr1 = lpb + (size_t)(v1 >> 2) * Tn + 4 * (v1 & 3);
            const float* pr2 = lpb + (size_t)(v2 >> 2) * Tn + 4 * (v2 & 3);
            const float* pr3 = lpb + (size_t)(v3 >> 2) * Tn + 4 * (v3 & 3);
            const float* pr4 = lpb + (size_t)(v4 >> 2) * Tn + 4 * (v4 & 3);
            const float* pr5 = lpb + (size_t)(v5 >> 2) * Tn + 4 * (v5 & 3);
            // col = l ^ (16*bit2(t)); bit2(t) = v&1 for this slot mapping
            int c0 = (4 * (v0 & 3)) * 256 + ((v0 >> 2) ^ ((v0 & 1) << 4));
            int c1 = (4 * (v1 & 3)) * 256 + ((v1 >> 2) ^ ((v1 & 1) << 4));
            int c2 = (4 * (v2 & 3)) * 256 + ((v2 >> 2) ^ ((v2 & 1) << 4));
            int c3 = (4 * (v3 & 3)) * 256 + ((v3 >> 2) ^ ((v3 & 1) << 4));
            int c4 = (4 * (v4 & 3)) * 256 + ((v4 >> 2) ^ ((v4 & 1) << 4));
            int c5 = (4 * (v5 & 3)) * 256 + ((v5 >> 2) ^ ((v5 & 1) << 4));
            float4 xh0, xh1, xh2, xh3, xh4, xh5;

            PLOAD(0) PWRITE(0)                 // prologue: chunks 0,1 in LDS; chunk 2 in regs
            PLOAD(1) PWRITE(1)
            PLOAD(2)
            asm volatile("s_waitcnt lgkmcnt(0)" ::: "memory");
            BARRIER();

            for (int k = 0; k < 128; ++k) {
                if (k <= 125) PWRITE(k + 2)    // write chunk staged last iteration
                if (k <= 124) PLOAD(k + 3)     // loads span the barrier (raw s_barrier)
                asm volatile("s_waitcnt lgkmcnt(0)" ::: "memory");
                BARRIER();
            }
        }
    } else if (bid < 32 + 1024) {
        // ---------------- guided-attention loss partials (independent blocks) ----------------
        const int N4 = Bn * Tn * Ln / 4;
        int j = bid - 32;
        int idx = j * 256 + tid;
        int stride = 1024 * 256;
        float acc = 0.f;
        for (int v = idx; v < N4; v += stride) {
            int flat = v << 2;                   // att is (B, T, L)
            int b  = flat >> 19;
            int t  = (flat >> 8) & (Tn - 1);
            int l0 = flat & (Ln - 1);
            int ili = ilen[b];
            int oli = olen[b];
            if (t >= oli) continue;
            float il = (float)ili, ol = (float)oli;
            float tf = (float)t / ol;
            float4 a = reinterpret_cast<const float4*>(att)[v];
            #pragma unroll
            for (int c = 0; c < 4; ++c) {
                int l = l0 + c;
                float av = (c == 0) ? a.x : (c == 1) ? a.y : (c == 2) ? a.z : a.w;
                if (l < ili) {
                    float d = (float)l / il - tf;
                    acc += (1.f - __expf(-d * d * 3.125f)) * av;
                }
            }
        }
        for (int off = 32; off > 0; off >>= 1) acc += __shfl_down(acc, off, 64);
        float* sw = smem;
        if ((tid & 63) == 0) sw[tid >> 6] = acc;
        __syncthreads();
        if (tid == 0) partial[j] = (sw[0] + sw[1]) + (sw[2] + sw[3]);
    } else {
        // -------- zero-fill riders: 16 blocks, issue-rate-throttled (~1.2 TB/s) --------
        const int NZ = (Bn * Ln * Tn) / 4;       // 2,097,152 float4 groups
        int j = bid - 1056;                       // 0..15
        float4 z = make_float4(0.f, 0.f, 0.f, 0.f);
        for (int i = j * 256 + tid; i < NZ; i += 16 * 256)
            reinterpret_cast<float4*>(out)[i] = z;
        if (j == 0 && tid == 0) out[(size_t)Bn * Ln * Tn] = 0.f;  // last element
    }
}

// ===== tail: per-batch backtrack (LDS bits, lane-0 walk, 8-deep window)
//       + sparse ones-scatter + (block 0) final loss reduce. =====
__global__ void __launch_bounds__(256) k_tail(const uint64_t* __restrict__ bits,
                                              const int* __restrict__ ilen,
                                              const int* __restrict__ olen,
                                              const float* __restrict__ partial,
                                              float* __restrict__ out) {
    __shared__ uint64_t sb[Ln * TB];   // 64 KB bit store
    __shared__ int2 eb[Ln];            // per-row extents
    __shared__ float sw[4];
    int b = blockIdx.x, tid = threadIdx.x;
    eb[tid] = make_int2(1, 0);         // empty
    const ulonglong2* g = (const ulonglong2*)(bits + (size_t)b * (Ln * TB));
    ulonglong2* s2 = (ulonglong2*)sb;
    #pragma unroll
    for (int i = 0; i < 16; ++i) s2[i * 256 + tid] = g[i * 256 + tid];
    __syncthreads();

    if (tid == 0) {
        int tl = ilen[b], ml = olen[b];
        int r = tl - 1, hi = ml - 1, p = ml - 2;
        if (p < 0) { eb[r] = make_int2(0, hi); }
        else {
            int c = p >> 6, vd;
            uint64_t w0, w1, w2, w3, w4, w5, w6, w7;
            #define LDW(RR) __builtin_bitreverse64(sb[(RR) * TB + c])
            #define RELOAD() { \
                w0 = LDW(r); \
                w1 = LDW(r > 0 ? r - 1 : 0); \
                w2 = LDW(r > 1 ? r - 2 : 0); \
                w3 = LDW(r > 2 ? r - 3 : 0); \
                w4 = LDW(r > 3 ? r - 4 : 0); \
                w5 = LDW(r > 4 ? r - 5 : 0); \
                w6 = LDW(r > 5 ? r - 6 : 0); \
                w7 = LDW(r > 6 ? r - 7 : 0); \
                vd = 7; }
            RELOAD();
            while (true) {
                int pb = p & 63;
                uint64_t mask = (pb == 63) ? ~0ull : ((1ull << (pb + 1)) - 1ull);
                uint64_t mm = w0 & mask;
                if (mm == 0) {
                    p = (p & ~63) - 1;
                    if (p < 0) { eb[r] = make_int2(0, hi); break; }
                    c = p >> 6;
                    RELOAD();
                } else {
                    int q = 63 - __builtin_clzll(mm);
                    int tq = (p & ~63) + q;
                    eb[r] = make_int2(tq + 1, hi);
                    r -= 1;
                    if (r < 0) break;           // saturation: remaining rows stay empty
                    hi = tq;
                    p = tq - 1;
                    if (p < 0) { eb[r] = make_int2(0, hi); break; }
                    w0 = w1; w1 = w2; w2 = w3; w3 = w4; w4 = w5; w5 = w6; w6 = w7;
                    vd -= 1;
                    int nc = p >> 6;
                    if (nc != c || vd == 0) { c = nc; RELOAD(); }
                }
            }
            #undef RELOAD
            #undef LDW
        }
    }
    __syncthreads();

    // sparse scatter: thread tid owns text row tid; write its run of ones
    {
        int2 e = eb[tid];
        float* orow = out + 1 + (((size_t)b * Ln + tid) << 11);
        for (int t = e.x; t <= e.y; ++t) orow[t] = 1.f;
    }

    // final deterministic loss reduce (block 0; zero-fill already wrote out[0]=0)
    if (b == 0) {
        float acc = 0.f;
        for (int i = tid; i < 1024; i += 256) acc += partial[i];
        for (int off = 32; off > 0; off >>= 1) acc += __shfl_down(acc, off, 64);
        if ((tid & 63) == 0) sw[tid >> 6] = acc;
        __syncthreads();
        if (tid == 0) {
            float tot = (sw[0] + sw[1]) + (sw[2] + sw[3]);
            int so = 0;
            for (int i = 0; i < Bn; ++i) so += olen[i];
            out[0] = tot / (float)so;
        }
    }
}

extern "C" void kernel_launch(void* const* d_in, const int* in_sizes, int n_in,
                              void* d_out, int out_size, void* d_ws, size_t ws_size,
                              hipStream_t stream) {
    const float* logp = (const float*)d_in[0];
    const float* att  = (const float*)d_in[1];
    const int* tlen   = (const int*)d_in[2];
    const int* mlen   = (const int*)d_in[3];
    float* out = (float*)d_out;
    uint64_t* bits = (uint64_t*)d_ws;                            // 2 MB
    float* partial = (float*)((char*)d_ws + 2097152);            // 4 KB

    // 1) mega: forward DP (r14 exact) + loss partials + issue-throttled zero riders
    k_mega<<<32 + 1024 + 16, 256, 0, stream>>>(logp, att, tlen, mlen,
                                               bits, partial, out);
    // 2) tail: backtrack (8-deep window) + sparse ones-scatter + final loss reduce
    k_tail<<<Bn, 256, 0, stream>>>(bits, tlen, mlen, partial, out);
}

// Round 21
// 130.060 us; speedup vs baseline: 1.4261x; 1.0020x over previous
//
#include <hip/hip_runtime.h>
#include <cstdint>

#define NEG (-1e12f)
constexpr int Bn = 32, Ln = 256, Tn = 2048;
constexpr int TB = Tn / 64;                 // 32 uint64 words of t-bits per text row

// d_ws layout (bytes):
//   bits    @ 0       : 32*256*32*8 = 2,097,152
//   partial @ 2097152 : 1024 floats (4 KB)

// lane i <- lane (i-1)&63  (wave_ror:1) : torch-wrap neighbor for the bit compare
__device__ inline float dpp_ror1(float x) {
    int xi = __float_as_int(x);
    return __int_as_float(__builtin_amdgcn_update_dpp(xi, xi, 0x13C, 0xF, 0xF, false));
}

__device__ inline uint32_t lds_off(const void* p) {
    return (uint32_t)(uintptr_t)(__attribute__((address_space(3))) const void*)p;
}

// raw barrier: NO implicit counter drain (producers' global loads stay in flight)
#define BARRIER() { asm volatile("" ::: "memory"); \
                    __builtin_amdgcn_s_barrier(); \
                    asm volatile("" ::: "memory"); }

// swizzled ds_read_b128: element (t,l) at col l ^ (16*bit2(t));
// lane block byte = (16*lane) ^ (64*bit2(row)).  ROW, BUF compile-time.
#define DSRX(DST, ROW, BUF) \
    asm volatile("ds_read_b128 %0, %1 offset:%c2" \
        : "=&v"(DST) \
        : "v"((((ROW) >> 2) & 1) ? vxb : vxa), \
          "i"((BUF) * 16384 + ((ROW) & 15) * 1024));

// coarse consume gate: once per 4 steps (r13-proven)
#define W4 { asm volatile("s_waitcnt lgkmcnt(4)"); __builtin_amdgcn_sched_barrier(0); }

// shift-accumulate one comparison bit: ACC = (ACC<<1) | (X > Y).  (r14-proven;
// vcc chain fully pipelined — beats the 3-op path, r15.) Bits land MSB-first;
// the walk bit-reverses each word on load.
#define ABIT(ACC, X, Y) \
    asm("v_cmp_gt_f32 vcc, %1, %2\n\tv_addc_co_u32 %0, vcc, %0, %0, vcc" \
        : "+v"(ACC) : "v"(X), "v"(Y) : "vcc");

// r14-proven partial-deferral step with addc bit packing. S = t-64m (1..64).
#define STEPS(S, Q) { \
    if ((((S) - 1) & 32) == 0) { ABIT(a0hi, svp, pv0) } else { ABIT(a0lo, svp, pv0) } \
    float c3 = fmaxf(pv3, pv2) + (Q).w; \
    float sv = dpp_ror1(c3); \
    float c2 = fmaxf(pv2, pv1) + (Q).z; \
    float c1 = fmaxf(pv1, pv0) + (Q).y; \
    float lf = isl0 ? negc : svp; \
    float c0 = fmaxf(pv0, lf) + (Q).x; \
    if (((S) & 32) == 0) { \
        ABIT(a1hi, c0, c1) ABIT(a2hi, c1, c2) ABIT(a3hi, c2, c3) \
    } else { \
        ABIT(a1lo, c0, c1) ABIT(a2lo, c1, c2) ABIT(a3lo, c2, c3) \
    } \
    if ((S) == 63) { \
        bb[(size_t)(4 * lane + 1) * TB + m] = ((uint64_t)a1hi << 32) | a1lo; \
        bb[(size_t)(4 * lane + 2) * TB + m] = ((uint64_t)a2hi << 32) | a2lo; \
        bb[(size_t)(4 * lane + 3) * TB + m] = ((uint64_t)a3hi << 32) | a3lo; \
        a1lo = a1hi = a2lo = a2hi = a3lo = a3hi = 0; \
    } \
    if ((S) == 64) { \
        bb[(size_t)(4 * lane + 0) * TB + m] = ((uint64_t)a0hi << 32) | a0lo; \
        a0lo = a0hi = 0; \
    } \
    pv0 = c0; pv1 = c1; pv2 = c2; pv3 = c3; svp = sv; }

// 16 DP steps of chunk c = 4m+I (buffer I); 8 slots, 4-step groups (r13 schedule)
#define COMP16X(I) { \
    W4 \
    STEPS(16*(I)+ 1, qq0) STEPS(16*(I)+ 2, qq1) STEPS(16*(I)+ 3, qq2) STEPS(16*(I)+ 4, qq3) \
    DSRX(qq0,  9, (I)) DSRX(qq1, 10, (I)) DSRX(qq2, 11, (I)) DSRX(qq3, 12, (I)) \
    W4 \
    STEPS(16*(I)+ 5, qq4) STEPS(16*(I)+ 6, qq5) STEPS(16*(I)+ 7, qq6) STEPS(16*(I)+ 8, qq7) \
    DSRX(qq4, 13, (I)) DSRX(qq5, 14, (I)) DSRX(qq6, 15, (I)) DSRX(qq7,  0, ((I)+1)&3) \
    W4 \
    STEPS(16*(I)+ 9, qq0) STEPS(16*(I)+10, qq1) STEPS(16*(I)+11, qq2) STEPS(16*(I)+12, qq3) \
    DSRX(qq0,  1, ((I)+1)&3) DSRX(qq1,  2, ((I)+1)&3) DSRX(qq2,  3, ((I)+1)&3) DSRX(qq3,  4, ((I)+1)&3) \
    W4 \
    STEPS(16*(I)+13, qq4) STEPS(16*(I)+14, qq5) STEPS(16*(I)+15, qq6) STEPS(16*(I)+16, qq7) \
    DSRX(qq4,  5, ((I)+1)&3) DSRX(qq5,  6, ((I)+1)&3) DSRX(qq6,  7, ((I)+1)&3) DSRX(qq7,  8, ((I)+1)&3) \
    BARRIER() }

// producer reg-staged load of chunk P into reg set A or B (6 float4/thread)
#define PLOADA(P) { \
    xa0 = *(const float4*)(pr0 + 16 * (P)); \
    xa1 = *(const float4*)(pr1 + 16 * (P)); \
    xa2 = *(const float4*)(pr2 + 16 * (P)); \
    xa3 = *(const float4*)(pr3 + 16 * (P)); \
    xa4 = *(const float4*)(pr4 + 16 * (P)); \
    if (six) xa5 = *(const float4*)(pr5 + 16 * (P)); }

#define PLOADB(P) { \
    xb0 = *(const float4*)(pr0 + 16 * (P)); \
    xb1 = *(const float4*)(pr1 + 16 * (P)); \
    xb2 = *(const float4*)(pr2 + 16 * (P)); \
    xb3 = *(const float4*)(pr3 + 16 * (P)); \
    xb4 = *(const float4*)(pr4 + 16 * (P)); \
    if (six) xb5 = *(const float4*)(pr5 + 16 * (P)); }

#define PW1(XH, CC) { float* rq = rr + (CC); \
    rq[0] = (XH).x; rq[256] = (XH).y; rq[512] = (XH).z; rq[768] = (XH).w; }

#define PWRITEA(P) { \
    float* rr = smem + ((P) & 3) * 4096; \
    PW1(xa0, c0) PW1(xa1, c1) PW1(xa2, c2) PW1(xa3, c3) PW1(xa4, c4) \
    if (six) PW1(xa5, c5) }

#define PWRITEB(P) { \
    float* rr = smem + ((P) & 3) * 4096; \
    PW1(xb0, c0) PW1(xb1, c1) PW1(xb2, c2) PW1(xb3, c3) PW1(xb4, c4) \
    if (six) PW1(xb5, c5) }

#define PWB { asm volatile("s_waitcnt lgkmcnt(0)" ::: "memory"); BARRIER(); }

// ===== mega: 0..31 forward+staging | 32..1055 loss | 1056..1071 zero-fill =====
// smem = 96 KB: 1 block/CU (r14-proven). Producers stage TWO chunks ahead in
// registers (~1600 cy latency slack vs ~800) so background write traffic can
// no longer push HBM read latency past the per-chunk budget.
__global__ void __launch_bounds__(256, 1) k_mega(
        const float* __restrict__ logp, const float* __restrict__ att,
        const int* __restrict__ ilen, const int* __restrict__ olen,
        uint64_t* __restrict__ bits, float* __restrict__ partial,
        float* __restrict__ out) {
    __shared__ __align__(16) float smem[24576];   // 96 KB (ring = first 64 KB)
    int bid = blockIdx.x, tid = threadIdx.x;

    if (bid < 32) {
        int b = bid;
        if (tid < 64) {
            // ---------------- DP consumer wave (r14-verbatim) ----------------
            __builtin_amdgcn_s_setprio(1);
            int lane = tid;
            bool isl0 = (lane == 0);
            uint64_t* bb = bits + (size_t)b * (Ln * TB);
            const float negc = NEG;
            uint32_t lb = lds_off(smem) + (uint32_t)(lane * 16);
            uint32_t vxa = lb, vxb = lb ^ 64;     // swizzle base pair

            float pv0, pv1, pv2, pv3, svp;
            uint32_t a0lo = 0, a0hi = 0, a1lo = 0, a1hi = 0;
            uint32_t a2lo = 0, a2hi = 0, a3lo = 0, a3hi = 0;

            // peeled t = 0: row0 = logp[b,0,0], others NEG.
            {
                float lp00 = logp[(size_t)b * (Ln * Tn)];
                pv0 = isl0 ? lp00 : NEG;
                pv1 = NEG; pv2 = NEG; pv3 = NEG;
                svp = dpp_ror1(pv3);               // all NEG
                a1hi = (pv0 > pv1) ? 1u : 0u;      // bit(0, 4*lane+1)
                a2hi = (pv1 > pv2) ? 1u : 0u;      // 0
                a3hi = (pv2 > pv3) ? 1u : 0u;      // 0
            }

            BARRIER();                             // chunks 0,1 in LDS
            float4 qq0, qq1, qq2, qq3, qq4, qq5, qq6, qq7;
            DSRX(qq0, 1, 0) DSRX(qq1, 2, 0) DSRX(qq2, 3, 0) DSRX(qq3, 4, 0)
            DSRX(qq4, 5, 0) DSRX(qq5, 6, 0) DSRX(qq6, 7, 0) DSRX(qq7, 8, 0)

            for (int m = 0; m < 32; ++m) {
                COMP16X(0) COMP16X(1) COMP16X(2) COMP16X(3)
            }
            asm volatile("s_waitcnt vmcnt(0)" ::: "memory");  // bit flushes visible
        } else {
            // ------ producer waves: 2-chunk-deep reg staging (ping-pong sets) ------
            int tid2 = tid - 64;                         // 0..191
            bool six = (tid2 < 64);                      // wave-uniform extra element
            const float* lpb = logp + (size_t)b * (Ln * Tn);
            int v0 = tid2, v1 = tid2 + 192, v2 = tid2 + 384,
                v3 = tid2 + 576, v4 = tid2 + 768, v5 = tid2 + 960;
            const float* pr0 = lpb + (size_t)(v0 >> 2) * Tn + 4 * (v0 & 3);
            const float* pr1 = lpb + (size_t)(v1 >> 2) * Tn + 4 * (v1 & 3);
            const float* pr2 = lpb + (size_t)(v2 >> 2) * Tn + 4 * (v2 & 3);
            const float* pr3 = lpb + (size_t)(v3 >> 2) * Tn + 4 * (v3 & 3);
            const float* pr4 = lpb + (size_t)(v4 >> 2) * Tn + 4 * (v4 & 3);
            const float* pr5 = lpb + (size_t)(v5 >> 2) * Tn + 4 * (v5 & 3);
            // col = l ^ (16*bit2(t)); bit2(t) = v&1 for this slot mapping
            int c0 = (4 * (v0 & 3)) * 256 + ((v0 >> 2) ^ ((v0 & 1) << 4));
            int c1 = (4 * (v1 & 3)) * 256 + ((v1 >> 2) ^ ((v1 & 1) << 4));
            int c2 = (4 * (v2 & 3)) * 256 + ((v2 >> 2) ^ ((v2 & 1) << 4));
            int c3 = (4 * (v3 & 3)) * 256 + ((v3 >> 2) ^ ((v3 & 1) << 4));
            int c4 = (4 * (v4 & 3)) * 256 + ((v4 >> 2) ^ ((v4 & 1) << 4));
            int c5 = (4 * (v5 & 3)) * 256 + ((v5 >> 2) ^ ((v5 & 1) << 4));
            float4 xa0, xa1, xa2, xa3, xa4, xa5;
            float4 xb0, xb1, xb2, xb3, xb4, xb5;

            PLOADA(0) PWRITEA(0)               // prologue: chunks 0,1 in LDS;
            PLOADA(1) PWRITEA(1)               // chunks 2,3 staged in regs (A,B)
            PLOADA(2)
            PLOADB(3)
            PWB

            // 62 unrolled pairs: k = 0..123 (write k+2, load k+4, barrier)
            for (int kk = 0; kk < 62; ++kk) {
                PWRITEA(2 * kk + 2) PLOADA(2 * kk + 4) PWB
                PWRITEB(2 * kk + 3) PLOADB(2 * kk + 5) PWB
            }
            PWRITEA(126) PWB                   // k = 124
            PWRITEB(127) PWB                   // k = 125
            PWB PWB                            // k = 126, 127 (barrier-only)
        }
    } else if (bid < 32 + 1024) {
        // ---------------- guided-attention loss partials (independent blocks) ----------------
        const int N4 = Bn * Tn * Ln / 4;
        int j = bid - 32;
        int idx = j * 256 + tid;
        int stride = 1024 * 256;
        float acc = 0.f;
        for (int v = idx; v < N4; v += stride) {
            int flat = v << 2;                   // att is (B, T, L)
            int b  = flat >> 19;
            int t  = (flat >> 8) & (Tn - 1);
            int l0 = flat & (Ln - 1);
            int ili = ilen[b];
            int oli = olen[b];
            if (t >= oli) continue;
            float il = (float)ili, ol = (float)oli;
            float tf = (float)t / ol;
            float4 a = reinterpret_cast<const float4*>(att)[v];
            #pragma unroll
            for (int c = 0; c < 4; ++c) {
                int l = l0 + c;
                float av = (c == 0) ? a.x : (c == 1) ? a.y : (c == 2) ? a.z : a.w;
                if (l < ili) {
                    float d = (float)l / il - tf;
                    acc += (1.f - __expf(-d * d * 3.125f)) * av;
                }
            }
        }
        for (int off = 32; off > 0; off >>= 1) acc += __shfl_down(acc, off, 64);
        float* sw = smem;
        if ((tid & 63) == 0) sw[tid >> 6] = acc;
        __syncthreads();
        if (tid == 0) partial[j] = (sw[0] + sw[1]) + (sw[2] + sw[3]);
    } else {
        // -------- zero-fill riders: 16 blocks, issue-rate-throttled --------
        const int NZ = (Bn * Ln * Tn) / 4;       // 2,097,152 float4 groups
        int j = bid - 1056;                       // 0..15
        float4 z = make_float4(0.f, 0.f, 0.f, 0.f);
        for (int i = j * 256 + tid; i < NZ; i += 16 * 256)
            reinterpret_cast<float4*>(out)[i] = z;
        if (j == 0 && tid == 0) out[(size_t)Bn * Ln * Tn] = 0.f;  // last element
    }
}

// ===== tail: per-batch backtrack (LDS bits, lane-0 walk, 8-deep window)
//       + sparse ones-scatter + (block 0) final loss reduce. =====
__global__ void __launch_bounds__(256) k_tail(const uint64_t* __restrict__ bits,
                                              const int* __restrict__ ilen,
                                              const int* __restrict__ olen,
                                              const float* __restrict__ partial,
                                              float* __restrict__ out) {
    __shared__ uint64_t sb[Ln * TB];   // 64 KB bit store
    __shared__ int2 eb[Ln];            // per-row extents
    __shared__ float sw[4];
    int b = blockIdx.x, tid = threadIdx.x;
    eb[tid] = make_int2(1, 0);         // empty
    const ulonglong2* g = (const ulonglong2*)(bits + (size_t)b * (Ln * TB));
    ulonglong2* s2 = (ulonglong2*)sb;
    #pragma unroll
    for (int i = 0; i < 16; ++i) s2[i * 256 + tid] = g[i * 256 + tid];
    __syncthreads();

    if (tid == 0) {
        int tl = ilen[b], ml = olen[b];
        int r = tl - 1, hi = ml - 1, p = ml - 2;
        if (p < 0) { eb[r] = make_int2(0, hi); }
        else {
            int c = p >> 6, vd;
            uint64_t w0, w1, w2, w3, w4, w5, w6, w7;
            #define LDW(RR) __builtin_bitreverse64(sb[(RR) * TB + c])
            #define RELOAD() { \
                w0 = LDW(r); \
                w1 = LDW(r > 0 ? r - 1 : 0); \
                w2 = LDW(r > 1 ? r - 2 : 0); \
                w3 = LDW(r > 2 ? r - 3 : 0); \
                w4 = LDW(r > 3 ? r - 4 : 0); \
                w5 = LDW(r > 4 ? r - 5 : 0); \
                w6 = LDW(r > 5 ? r - 6 : 0); \
                w7 = LDW(r > 6 ? r - 7 : 0); \
                vd = 7; }
            RELOAD();
            while (true) {
                int pb = p & 63;
                uint64_t mask = (pb == 63) ? ~0ull : ((1ull << (pb + 1)) - 1ull);
                uint64_t mm = w0 & mask;
                if (mm == 0) {
                    p = (p & ~63) - 1;
                    if (p < 0) { eb[r] = make_int2(0, hi); break; }
                    c = p >> 6;
                    RELOAD();
                } else {
                    int q = 63 - __builtin_clzll(mm);
                    int tq = (p & ~63) + q;
                    eb[r] = make_int2(tq + 1, hi);
                    r -= 1;
                    if (r < 0) break;           // saturation: remaining rows stay empty
                    hi = tq;
                    p = tq - 1;
                    if (p < 0) { eb[r] = make_int2(0, hi); break; }
                    w0 = w1; w1 = w2; w2 = w3; w3 = w4; w4 = w5; w5 = w6; w6 = w7;
                    vd -= 1;
                    int nc = p >> 6;
                    if (nc != c || vd == 0) { c = nc; RELOAD(); }
                }
            }
            #undef RELOAD
            #undef LDW
        }
    }
    __syncthreads();

    // sparse scatter: thread tid owns text row tid; write its run of ones
    {
        int2 e = eb[tid];
        float* orow = out + 1 + (((size_t)b * Ln + tid) << 11);
        for (int t = e.x; t <= e.y; ++t) orow[t] = 1.f;
    }

    // final deterministic loss reduce (block 0; zero-fill already wrote out[0]=0)
    if (b == 0) {
        float acc = 0.f;
        for (int i = tid; i < 1024; i += 256) acc += partial[i];
        for (int off = 32; off > 0; off >>= 1) acc += __shfl_down(acc, off, 64);
        if ((tid & 63) == 0) sw[tid >> 6] = acc;
        __syncthreads();
        if (tid == 0) {
            float tot = (sw[0] + sw[1]) + (sw[2] + sw[3]);
            int so = 0;
            for (int i = 0; i < Bn; ++i) so += olen[i];
            out[0] = tot / (float)so;
        }
    }
}

extern "C" void kernel_launch(void* const* d_in, const int* in_sizes, int n_in,
                              void* d_out, int out_size, void* d_ws, size_t ws_size,
                              hipStream_t stream) {
    const float* logp = (const float*)d_in[0];
    const float* att  = (const float*)d_in[1];
    const int* tlen   = (const int*)d_in[2];
    const int* mlen   = (const int*)d_in[3];
    float* out = (float*)d_out;
    uint64_t* bits = (uint64_t*)d_ws;                            // 2 MB
    float* partial = (float*)((char*)d_ws + 2097152);            // 4 KB

    // 1) mega: forward DP (2-chunk-deep producer staging) + loss + zero riders
    k_mega<<<32 + 1024 + 16, 256, 0, stream>>>(logp, att, tlen, mlen,
                                               bits, partial, out);
    // 2) tail: backtrack (8-deep window) + sparse ones-scatter + final loss reduce
    k_tail<<<Bn, 256, 0, stream>>>(bits, tlen, mlen, partial, out);
}

// Round 22
// 129.304 us; speedup vs baseline: 1.4345x; 1.0058x over previous
//
#include <hip/hip_runtime.h>
#include <cstdint>

#define NEG (-1e12f)
constexpr int Bn = 32, Ln = 256, Tn = 2048;
constexpr int TB = Tn / 64;                 // 32 uint64 words of t-bits per text row

// d_ws layout (bytes):
//   bits    @ 0       : 32*256*32*8 = 2,097,152
//   partial @ 2097152 : 1024 floats (4 KB)

// lane i <- lane (i-1)&63  (wave_ror:1) : torch-wrap neighbor for the bit compare
__device__ inline float dpp_ror1(float x) {
    int xi = __float_as_int(x);
    return __int_as_float(__builtin_amdgcn_update_dpp(xi, xi, 0x13C, 0xF, 0xF, false));
}

__device__ inline uint32_t lds_off(const void* p) {
    return (uint32_t)(uintptr_t)(__attribute__((address_space(3))) const void*)p;
}

// raw barrier: NO implicit counter drain (producers' global loads stay in flight)
#define BARRIER() { asm volatile("" ::: "memory"); \
                    __builtin_amdgcn_s_barrier(); \
                    asm volatile("" ::: "memory"); }

// swizzled ds_read_b128: element (t,l) at col l ^ (16*bit2(t));
// lane block byte = (16*lane) ^ (64*bit2(row)).  ROW, BUF compile-time.
#define DSRX(DST, ROW, BUF) \
    asm volatile("ds_read_b128 %0, %1 offset:%c2" \
        : "=&v"(DST) \
        : "v"((((ROW) >> 2) & 1) ? vxb : vxa), \
          "i"((BUF) * 16384 + ((ROW) & 15) * 1024));

// coarse consume gate: once per 4 steps (r13-proven)
#define W4 { asm volatile("s_waitcnt lgkmcnt(4)"); __builtin_amdgcn_sched_barrier(0); }

// shift-accumulate one comparison bit: ACC = (ACC<<1) | (X > Y).  (r14-proven;
// vcc chain fully pipelined — beats the 3-op path, r15.) Bits land MSB-first;
// the walk bit-reverses each word on load.
#define ABIT(ACC, X, Y) \
    asm("v_cmp_gt_f32 vcc, %1, %2\n\tv_addc_co_u32 %0, vcc, %0, %0, vcc" \
        : "+v"(ACC) : "v"(X), "v"(Y) : "vcc");

// r14-proven partial-deferral step with addc bit packing. S = t-64m (1..64).
#define STEPS(S, Q) { \
    if ((((S) - 1) & 32) == 0) { ABIT(a0hi, svp, pv0) } else { ABIT(a0lo, svp, pv0) } \
    float c3 = fmaxf(pv3, pv2) + (Q).w; \
    float sv = dpp_ror1(c3); \
    float c2 = fmaxf(pv2, pv1) + (Q).z; \
    float c1 = fmaxf(pv1, pv0) + (Q).y; \
    float lf = isl0 ? negc : svp; \
    float c0 = fmaxf(pv0, lf) + (Q).x; \
    if (((S) & 32) == 0) { \
        ABIT(a1hi, c0, c1) ABIT(a2hi, c1, c2) ABIT(a3hi, c2, c3) \
    } else { \
        ABIT(a1lo, c0, c1) ABIT(a2lo, c1, c2) ABIT(a3lo, c2, c3) \
    } \
    if ((S) == 63) { \
        bb[(size_t)(4 * lane + 1) * TB + m] = ((uint64_t)a1hi << 32) | a1lo; \
        bb[(size_t)(4 * lane + 2) * TB + m] = ((uint64_t)a2hi << 32) | a2lo; \
        bb[(size_t)(4 * lane + 3) * TB + m] = ((uint64_t)a3hi << 32) | a3lo; \
        a1lo = a1hi = a2lo = a2hi = a3lo = a3hi = 0; \
    } \
    if ((S) == 64) { \
        bb[(size_t)(4 * lane + 0) * TB + m] = ((uint64_t)a0hi << 32) | a0lo; \
        a0lo = a0hi = 0; \
    } \
    pv0 = c0; pv1 = c1; pv2 = c2; pv3 = c3; svp = sv; }

// 16 DP steps of chunk c = 4m+I (buffer I); 8 slots, 4-step groups (r13 schedule)
#define COMP16X(I) { \
    W4 \
    STEPS(16*(I)+ 1, qq0) STEPS(16*(I)+ 2, qq1) STEPS(16*(I)+ 3, qq2) STEPS(16*(I)+ 4, qq3) \
    DSRX(qq0,  9, (I)) DSRX(qq1, 10, (I)) DSRX(qq2, 11, (I)) DSRX(qq3, 12, (I)) \
    W4 \
    STEPS(16*(I)+ 5, qq4) STEPS(16*(I)+ 6, qq5) STEPS(16*(I)+ 7, qq6) STEPS(16*(I)+ 8, qq7) \
    DSRX(qq4, 13, (I)) DSRX(qq5, 14, (I)) DSRX(qq6, 15, (I)) DSRX(qq7,  0, ((I)+1)&3) \
    W4 \
    STEPS(16*(I)+ 9, qq0) STEPS(16*(I)+10, qq1) STEPS(16*(I)+11, qq2) STEPS(16*(I)+12, qq3) \
    DSRX(qq0,  1, ((I)+1)&3) DSRX(qq1,  2, ((I)+1)&3) DSRX(qq2,  3, ((I)+1)&3) DSRX(qq3,  4, ((I)+1)&3) \
    W4 \
    STEPS(16*(I)+13, qq4) STEPS(16*(I)+14, qq5) STEPS(16*(I)+15, qq6) STEPS(16*(I)+16, qq7) \
    DSRX(qq4,  5, ((I)+1)&3) DSRX(qq5,  6, ((I)+1)&3) DSRX(qq6,  7, ((I)+1)&3) DSRX(qq7,  8, ((I)+1)&3) \
    BARRIER() }

// producer reg-staged load of chunk P into reg set A or B (6 float4/thread)
#define PLOADA(P) { \
    xa0 = *(const float4*)(pr0 + 16 * (P)); \
    xa1 = *(const float4*)(pr1 + 16 * (P)); \
    xa2 = *(const float4*)(pr2 + 16 * (P)); \
    xa3 = *(const float4*)(pr3 + 16 * (P)); \
    xa4 = *(const float4*)(pr4 + 16 * (P)); \
    if (six) xa5 = *(const float4*)(pr5 + 16 * (P)); }

#define PLOADB(P) { \
    xb0 = *(const float4*)(pr0 + 16 * (P)); \
    xb1 = *(const float4*)(pr1 + 16 * (P)); \
    xb2 = *(const float4*)(pr2 + 16 * (P)); \
    xb3 = *(const float4*)(pr3 + 16 * (P)); \
    xb4 = *(const float4*)(pr4 + 16 * (P)); \
    if (six) xb5 = *(const float4*)(pr5 + 16 * (P)); }

#define PW1(XH, CC) { float* rq = rr + (CC); \
    rq[0] = (XH).x; rq[256] = (XH).y; rq[512] = (XH).z; rq[768] = (XH).w; }

#define PWRITEA(P) { \
    float* rr = smem + ((P) & 3) * 4096; \
    PW1(xa0, c0) PW1(xa1, c1) PW1(xa2, c2) PW1(xa3, c3) PW1(xa4, c4) \
    if (six) PW1(xa5, c5) }

#define PWRITEB(P) { \
    float* rr = smem + ((P) & 3) * 4096; \
    PW1(xb0, c0) PW1(xb1, c1) PW1(xb2, c2) PW1(xb3, c3) PW1(xb4, c4) \
    if (six) PW1(xb5, c5) }

#define PWB { asm volatile("s_waitcnt lgkmcnt(0)" ::: "memory"); BARRIER(); }

// ===== mega: 0..31 forward+staging | 32..1055 loss | 1056..1087 zero-fill =====
// smem = 96 KB: 1 block/CU (r14-proven). 32 zero riders (2 MB each): riders
// finish ~60 us (inside forward's ~92) at a steady ~2.4 TB/s aggregate.
__global__ void __launch_bounds__(256, 1) k_mega(
        const float* __restrict__ logp, const float* __restrict__ att,
        const int* __restrict__ ilen, const int* __restrict__ olen,
        uint64_t* __restrict__ bits, float* __restrict__ partial,
        float* __restrict__ out) {
    __shared__ __align__(16) float smem[24576];   // 96 KB (ring = first 64 KB)
    int bid = blockIdx.x, tid = threadIdx.x;

    if (bid < 32) {
        int b = bid;
        if (tid < 64) {
            // ---------------- DP consumer wave (r14-verbatim) ----------------
            __builtin_amdgcn_s_setprio(1);
            int lane = tid;
            bool isl0 = (lane == 0);
            uint64_t* bb = bits + (size_t)b * (Ln * TB);
            const float negc = NEG;
            uint32_t lb = lds_off(smem) + (uint32_t)(lane * 16);
            uint32_t vxa = lb, vxb = lb ^ 64;     // swizzle base pair

            float pv0, pv1, pv2, pv3, svp;
            uint32_t a0lo = 0, a0hi = 0, a1lo = 0, a1hi = 0;
            uint32_t a2lo = 0, a2hi = 0, a3lo = 0, a3hi = 0;

            // peeled t = 0: row0 = logp[b,0,0], others NEG.
            {
                float lp00 = logp[(size_t)b * (Ln * Tn)];
                pv0 = isl0 ? lp00 : NEG;
                pv1 = NEG; pv2 = NEG; pv3 = NEG;
                svp = dpp_ror1(pv3);               // all NEG
                a1hi = (pv0 > pv1) ? 1u : 0u;      // bit(0, 4*lane+1)
                a2hi = (pv1 > pv2) ? 1u : 0u;      // 0
                a3hi = (pv2 > pv3) ? 1u : 0u;      // 0
            }

            BARRIER();                             // chunks 0,1 in LDS
            float4 qq0, qq1, qq2, qq3, qq4, qq5, qq6, qq7;
            DSRX(qq0, 1, 0) DSRX(qq1, 2, 0) DSRX(qq2, 3, 0) DSRX(qq3, 4, 0)
            DSRX(qq4, 5, 0) DSRX(qq5, 6, 0) DSRX(qq6, 7, 0) DSRX(qq7, 8, 0)

            for (int m = 0; m < 32; ++m) {
                COMP16X(0) COMP16X(1) COMP16X(2) COMP16X(3)
            }
            asm volatile("s_waitcnt vmcnt(0)" ::: "memory");  // bit flushes visible
        } else {
            // ------ producer waves: 2-chunk-deep reg staging (ping-pong sets) ------
            int tid2 = tid - 64;                         // 0..191
            bool six = (tid2 < 64);                      // wave-uniform extra element
            const float* lpb = logp + (size_t)b * (Ln * Tn);
            int v0 = tid2, v1 = tid2 + 192, v2 = tid2 + 384,
                v3 = tid2 + 576, v4 = tid2 + 768, v5 = tid2 + 960;
            const float* pr0 = lpb + (size_t)(v0 >> 2) * Tn + 4 * (v0 & 3);
            const float* pr1 = lpb + (size_t)(v1 >> 2) * Tn + 4 * (v1 & 3);
            const float* pr2 = lpb + (size_t)(v2 >> 2) * Tn + 4 * (v2 & 3);
            const float* pr3 = lpb + (size_t)(v3 >> 2) * Tn + 4 * (v3 & 3);
            const float* pr4 = lpb + (size_t)(v4 >> 2) * Tn + 4 * (v4 & 3);
            const float* pr5 = lpb + (size_t)(v5 >> 2) * Tn + 4 * (v5 & 3);
            // col = l ^ (16*bit2(t)); bit2(t) = v&1 for this slot mapping
            int c0 = (4 * (v0 & 3)) * 256 + ((v0 >> 2) ^ ((v0 & 1) << 4));
            int c1 = (4 * (v1 & 3)) * 256 + ((v1 >> 2) ^ ((v1 & 1) << 4));
            int c2 = (4 * (v2 & 3)) * 256 + ((v2 >> 2) ^ ((v2 & 1) << 4));
            int c3 = (4 * (v3 & 3)) * 256 + ((v3 >> 2) ^ ((v3 & 1) << 4));
            int c4 = (4 * (v4 & 3)) * 256 + ((v4 >> 2) ^ ((v4 & 1) << 4));
            int c5 = (4 * (v5 & 3)) * 256 + ((v5 >> 2) ^ ((v5 & 1) << 4));
            float4 xa0, xa1, xa2, xa3, xa4, xa5;
            float4 xb0, xb1, xb2, xb3, xb4, xb5;

            PLOADA(0) PWRITEA(0)               // prologue: chunks 0,1 in LDS;
            PLOADA(1) PWRITEA(1)               // chunks 2,3 staged in regs (A,B)
            PLOADA(2)
            PLOADB(3)
            PWB

            // 62 unrolled pairs: k = 0..123 (write k+2, load k+4, barrier)
            for (int kk = 0; kk < 62; ++kk) {
                PWRITEA(2 * kk + 2) PLOADA(2 * kk + 4) PWB
                PWRITEB(2 * kk + 3) PLOADB(2 * kk + 5) PWB
            }
            PWRITEA(126) PWB                   // k = 124
            PWRITEB(127) PWB                   // k = 125
            PWB PWB                            // k = 126, 127 (barrier-only)
        }
    } else if (bid < 32 + 1024) {
        // ---------------- guided-attention loss partials (independent blocks) ----------------
        const int N4 = Bn * Tn * Ln / 4;
        int j = bid - 32;
        int idx = j * 256 + tid;
        int stride = 1024 * 256;
        float acc = 0.f;
        for (int v = idx; v < N4; v += stride) {
            int flat = v << 2;                   // att is (B, T, L)
            int b  = flat >> 19;
            int t  = (flat >> 8) & (Tn - 1);
            int l0 = flat & (Ln - 1);
            int ili = ilen[b];
            int oli = olen[b];
            if (t >= oli) continue;
            float il = (float)ili, ol = (float)oli;
            float tf = (float)t / ol;
            float4 a = reinterpret_cast<const float4*>(att)[v];
            #pragma unroll
            for (int c = 0; c < 4; ++c) {
                int l = l0 + c;
                float av = (c == 0) ? a.x : (c == 1) ? a.y : (c == 2) ? a.z : a.w;
                if (l < ili) {
                    float d = (float)l / il - tf;
                    acc += (1.f - __expf(-d * d * 3.125f)) * av;
                }
            }
        }
        for (int off = 32; off > 0; off >>= 1) acc += __shfl_down(acc, off, 64);
        float* sw = smem;
        if ((tid & 63) == 0) sw[tid >> 6] = acc;
        __syncthreads();
        if (tid == 0) partial[j] = (sw[0] + sw[1]) + (sw[2] + sw[3]);
    } else {
        // -------- zero-fill riders: 32 blocks (2 MB each, ~2.4 TB/s aggregate) --------
        const int NZ = (Bn * Ln * Tn) / 4;       // 2,097,152 float4 groups
        int j = bid - 1056;                       // 0..31
        float4 z = make_float4(0.f, 0.f, 0.f, 0.f);
        for (int i = j * 256 + tid; i < NZ; i += 32 * 256)
            reinterpret_cast<float4*>(out)[i] = z;
        if (j == 0 && tid == 0) out[(size_t)Bn * Ln * Tn] = 0.f;  // last element
    }
}

// ===== tail: per-batch backtrack (LDS bits, lane-0 walk, 8-deep window)
//       + sparse ones-scatter + (block 0) final loss reduce. =====
__global__ void __launch_bounds__(256) k_tail(const uint64_t* __restrict__ bits,
                                              const int* __restrict__ ilen,
                                              const int* __restrict__ olen,
                                              const float* __restrict__ partial,
                                              float* __restrict__ out) {
    __shared__ uint64_t sb[Ln * TB];   // 64 KB bit store
    __shared__ int2 eb[Ln];            // per-row extents
    __shared__ float sw[4];
    int b = blockIdx.x, tid = threadIdx.x;
    eb[tid] = make_int2(1, 0);         // empty
    const ulonglong2* g = (const ulonglong2*)(bits + (size_t)b * (Ln * TB));
    ulonglong2* s2 = (ulonglong2*)sb;
    #pragma unroll
    for (int i = 0; i < 16; ++i) s2[i * 256 + tid] = g[i * 256 + tid];
    __syncthreads();

    if (tid == 0) {
        int tl = ilen[b], ml = olen[b];
        int r = tl - 1, hi = ml - 1, p = ml - 2;
        if (p < 0) { eb[r] = make_int2(0, hi); }
        else {
            int c = p >> 6, vd;
            uint64_t w0, w1, w2, w3, w4, w5, w6, w7;
            #define LDW(RR) __builtin_bitreverse64(sb[(RR) * TB + c])
            #define RELOAD() { \
                w0 = LDW(r); \
                w1 = LDW(r > 0 ? r - 1 : 0); \
                w2 = LDW(r > 1 ? r - 2 : 0); \
                w3 = LDW(r > 2 ? r - 3 : 0); \
                w4 = LDW(r > 3 ? r - 4 : 0); \
                w5 = LDW(r > 4 ? r - 5 : 0); \
                w6 = LDW(r > 5 ? r - 6 : 0); \
                w7 = LDW(r > 6 ? r - 7 : 0); \
                vd = 7; }
            RELOAD();
            while (true) {
                int pb = p & 63;
                uint64_t mask = (pb == 63) ? ~0ull : ((1ull << (pb + 1)) - 1ull);
                uint64_t mm = w0 & mask;
                if (mm == 0) {
                    p = (p & ~63) - 1;
                    if (p < 0) { eb[r] = make_int2(0, hi); break; }
                    c = p >> 6;
                    RELOAD();
                } else {
                    int q = 63 - __builtin_clzll(mm);
                    int tq = (p & ~63) + q;
                    eb[r] = make_int2(tq + 1, hi);
                    r -= 1;
                    if (r < 0) break;           // saturation: remaining rows stay empty
                    hi = tq;
                    p = tq - 1;
                    if (p < 0) { eb[r] = make_int2(0, hi); break; }
                    w0 = w1; w1 = w2; w2 = w3; w3 = w4; w4 = w5; w5 = w6; w6 = w7;
                    vd -= 1;
                    int nc = p >> 6;
                    if (nc != c || vd == 0) { c = nc; RELOAD(); }
                }
            }
            #undef RELOAD
            #undef LDW
        }
    }
    __syncthreads();

    // sparse scatter: thread tid owns text row tid; write its run of ones
    {
        int2 e = eb[tid];
        float* orow = out + 1 + (((size_t)b * Ln + tid) << 11);
        for (int t = e.x; t <= e.y; ++t) orow[t] = 1.f;
    }

    // final deterministic loss reduce (block 0; zero-fill already wrote out[0]=0)
    if (b == 0) {
        float acc = 0.f;
        for (int i = tid; i < 1024; i += 256) acc += partial[i];
        for (int off = 32; off > 0; off >>= 1) acc += __shfl_down(acc, off, 64);
        if ((tid & 63) == 0) sw[tid >> 6] = acc;
        __syncthreads();
        if (tid == 0) {
            float tot = (sw[0] + sw[1]) + (sw[2] + sw[3]);
            int so = 0;
            for (int i = 0; i < Bn; ++i) so += olen[i];
            out[0] = tot / (float)so;
        }
    }
}

extern "C" void kernel_launch(void* const* d_in, const int* in_sizes, int n_in,
                              void* d_out, int out_size, void* d_ws, size_t ws_size,
                              hipStream_t stream) {
    const float* logp = (const float*)d_in[0];
    const float* att  = (const float*)d_in[1];
    const int* tlen   = (const int*)d_in[2];
    const int* mlen   = (const int*)d_in[3];
    float* out = (float*)d_out;
    uint64_t* bits = (uint64_t*)d_ws;                            // 2 MB
    float* partial = (float*)((char*)d_ws + 2097152);            // 4 KB

    // 1) mega: forward DP + loss partials + 32 zero-fill riders
    k_mega<<<32 + 1024 + 32, 256, 0, stream>>>(logp, att, tlen, mlen,
                                               bits, partial, out);
    // 2) tail: backtrack (8-deep window) + sparse ones-scatter + final loss reduce
    k_tail<<<Bn, 256, 0, stream>>>(bits, tlen, mlen, partial, out);
}